// Round 1
// baseline (99.480 us; speedup 1.0000x reference)
//
#include <hip/hip_runtime.h>

// VolatilityLoss: mean((std3(pred) - std3(targ))^2) over all sliding windows.
// B=512, S=8192, W=3, L=8190. Memory-bound: 128 MiB in, 4 B out.

constexpr int B = 512;
constexpr int S = 8192;
constexpr int W = 3;
constexpr int L = S - W + 1;              // 8190 windows per row
constexpr int CHUNK = 8;                  // windows per thread
constexpr int CHUNKS_PER_ROW = S / CHUNK; // 1024 (last chunk: 6 valid windows)
constexpr int THREADS = 256;
constexpr int TOTAL_CHUNKS = B * CHUNKS_PER_ROW; // 524288
constexpr int BLOCKS = TOTAL_CHUNKS / THREADS;   // 2048

// Unbiased std of 3 samples: var = ((a-b)^2 + (b-c)^2 + (a-c)^2) / 6
__device__ __forceinline__ float std3(float a, float b, float c) {
    float d0 = a - b, d1 = b - c, d2 = a - c;
    return sqrtf((d0 * d0 + d1 * d1 + d2 * d2) * (1.0f / 6.0f));
}

__global__ __launch_bounds__(THREADS) void vol_loss_kernel(
    const float* __restrict__ pred, const float* __restrict__ targ,
    float* __restrict__ out)
{
    const int c   = blockIdx.x * THREADS + threadIdx.x; // global chunk id
    const int row = c >> 10;                            // c / CHUNKS_PER_ROW
    const int cir = c & (CHUNKS_PER_ROW - 1);
    const int j0  = cir * CHUNK;                        // first window index in row

    const float* __restrict__ prow = pred + (size_t)row * S;
    const float* __restrict__ trow = targ + (size_t)row * S;

    float p[10], t[10];
    // chunk base is a multiple of 8 floats -> 16B-aligned float4 loads
    const float4 p0 = *(const float4*)(prow + j0);
    const float4 p1 = *(const float4*)(prow + j0 + 4);
    const float4 t0 = *(const float4*)(trow + j0);
    const float4 t1 = *(const float4*)(trow + j0 + 4);
    p[0] = p0.x; p[1] = p0.y; p[2] = p0.z; p[3] = p0.w;
    p[4] = p1.x; p[5] = p1.y; p[6] = p1.z; p[7] = p1.w;
    t[0] = t0.x; t[1] = t0.y; t[2] = t0.z; t[3] = t0.w;
    t[4] = t1.x; t[5] = t1.y; t[6] = t1.z; t[7] = t1.w;

    int nwin = L - j0;            // 8 for all chunks except the last per row (6)
    if (nwin > CHUNK) nwin = CHUNK;

    if (nwin == CHUNK) {
        // need x[j0+8], x[j0+9]; in-bounds only for non-tail chunks
        const float2 p2 = *(const float2*)(prow + j0 + 8);
        const float2 t2 = *(const float2*)(trow + j0 + 8);
        p[8] = p2.x; p[9] = p2.y;
        t[8] = t2.x; t[9] = t2.y;
    } else {
        p[8] = p[9] = t[8] = t[9] = 0.0f; // unused (masked below)
    }

    float acc = 0.0f;
    #pragma unroll
    for (int k = 0; k < CHUNK; ++k) {
        float sp = std3(p[k], p[k + 1], p[k + 2]);
        float st = std3(t[k], t[k + 1], t[k + 2]);
        float d  = sp - st;
        acc += (k < nwin) ? d * d : 0.0f;
    }

    // pre-scale by 1/(B*L) so the atomic sum IS the mean
    acc *= (1.0f / ((float)B * (float)L));

    // wave (64-lane) shuffle reduction
    #pragma unroll
    for (int off = 32; off > 0; off >>= 1)
        acc += __shfl_down(acc, off, 64);

    __shared__ float smem[THREADS / 64];
    const int lane = threadIdx.x & 63;
    const int wave = threadIdx.x >> 6;
    if (lane == 0) smem[wave] = acc;
    __syncthreads();
    if (threadIdx.x == 0) {
        float s = smem[0] + smem[1] + smem[2] + smem[3];
        atomicAdd(out, s);
    }
}

extern "C" void kernel_launch(void* const* d_in, const int* in_sizes, int n_in,
                              void* d_out, int out_size, void* d_ws, size_t ws_size,
                              hipStream_t stream) {
    const float* pred = (const float*)d_in[0];
    const float* targ = (const float*)d_in[1];
    float* out = (float*)d_out;

    // d_out is poisoned 0xAA before every timed launch — zero it (capture-safe)
    hipMemsetAsync(out, 0, sizeof(float), stream);

    vol_loss_kernel<<<BLOCKS, THREADS, 0, stream>>>(pred, targ, out);
}

// Round 2
// 76.423 us; speedup vs baseline: 1.3017x; 1.3017x over previous
//
#include <hip/hip_runtime.h>

// VolatilityLoss: mean((std3(pred) - std3(targ))^2) over sliding windows.
// B=512, S=8192, W=3, L=8190. Inputs: 2 x 16 MiB fp32 = 32 MiB total.
// Memory-bound roofline ~5.5 us @ 6.3 TB/s.
//
// R1: replaced 2048 same-address device-scope atomicAdds (theory: serialized
// cross-XCD RMW ~49 ns each ~= the whole 99 us) with per-block partials in
// d_ws + a tiny reducer kernel. Also dropped the 4B memset dispatch from the
// timed graph (reducer plain-stores the result).

constexpr int B = 512;
constexpr int S = 8192;
constexpr int W = 3;
constexpr int L = S - W + 1;              // 8190 windows per row
constexpr int CHUNK = 8;                  // windows per thread
constexpr int CHUNKS_PER_ROW = S / CHUNK; // 1024 (last chunk: 6 valid windows)
constexpr int THREADS = 256;
constexpr int TOTAL_CHUNKS = B * CHUNKS_PER_ROW; // 524288
constexpr int BLOCKS = TOTAL_CHUNKS / THREADS;   // 2048

// Unbiased std of 3 samples: var = ((a-b)^2 + (b-c)^2 + (a-c)^2) / 6
__device__ __forceinline__ float std3(float a, float b, float c) {
    float d0 = a - b, d1 = b - c, d2 = a - c;
    return sqrtf((d0 * d0 + d1 * d1 + d2 * d2) * (1.0f / 6.0f));
}

__global__ __launch_bounds__(THREADS) void vol_loss_main(
    const float* __restrict__ pred, const float* __restrict__ targ,
    float* __restrict__ partial)
{
    const int c   = blockIdx.x * THREADS + threadIdx.x; // global chunk id
    const int row = c >> 10;                            // c / CHUNKS_PER_ROW
    const int cir = c & (CHUNKS_PER_ROW - 1);
    const int j0  = cir * CHUNK;                        // first window index in row

    const float* __restrict__ prow = pred + (size_t)row * S;
    const float* __restrict__ trow = targ + (size_t)row * S;

    float p[10], t[10];
    const float4 p0 = *(const float4*)(prow + j0);
    const float4 p1 = *(const float4*)(prow + j0 + 4);
    const float4 t0 = *(const float4*)(trow + j0);
    const float4 t1 = *(const float4*)(trow + j0 + 4);
    p[0] = p0.x; p[1] = p0.y; p[2] = p0.z; p[3] = p0.w;
    p[4] = p1.x; p[5] = p1.y; p[6] = p1.z; p[7] = p1.w;
    t[0] = t0.x; t[1] = t0.y; t[2] = t0.z; t[3] = t0.w;
    t[4] = t1.x; t[5] = t1.y; t[6] = t1.z; t[7] = t1.w;

    int nwin = L - j0;            // 8 everywhere except last chunk per row (6)
    if (nwin > CHUNK) nwin = CHUNK;

    if (nwin == CHUNK) {
        const float2 p2 = *(const float2*)(prow + j0 + 8);
        const float2 t2 = *(const float2*)(trow + j0 + 8);
        p[8] = p2.x; p[9] = p2.y;
        t[8] = t2.x; t[9] = t2.y;
    } else {
        p[8] = p[9] = t[8] = t[9] = 0.0f;
    }

    float acc = 0.0f;
    #pragma unroll
    for (int k = 0; k < CHUNK; ++k) {
        float sp = std3(p[k], p[k + 1], p[k + 2]);
        float st = std3(t[k], t[k + 1], t[k + 2]);
        float d  = sp - st;
        acc += (k < nwin) ? d * d : 0.0f;
    }

    acc *= (1.0f / ((float)B * (float)L)); // pre-scale so the sum IS the mean

    // wave (64-lane) shuffle reduction
    #pragma unroll
    for (int off = 32; off > 0; off >>= 1)
        acc += __shfl_down(acc, off, 64);

    __shared__ float smem[THREADS / 64];
    const int lane = threadIdx.x & 63;
    const int wave = threadIdx.x >> 6;
    if (lane == 0) smem[wave] = acc;
    __syncthreads();
    if (threadIdx.x == 0)
        partial[blockIdx.x] = smem[0] + smem[1] + smem[2] + smem[3];
}

// Sum BLOCKS (=2048) partials -> out[0]. One block of 256 threads.
__global__ __launch_bounds__(256) void vol_loss_reduce(
    const float* __restrict__ partial, float* __restrict__ out)
{
    const float4 a = ((const float4*)partial)[threadIdx.x];        // 0..1023
    const float4 b = ((const float4*)partial)[threadIdx.x + 256];  // 1024..2047
    float acc = (a.x + a.y) + (a.z + a.w) + (b.x + b.y) + (b.z + b.w);

    #pragma unroll
    for (int off = 32; off > 0; off >>= 1)
        acc += __shfl_down(acc, off, 64);

    __shared__ float smem[4];
    const int lane = threadIdx.x & 63;
    const int wave = threadIdx.x >> 6;
    if (lane == 0) smem[wave] = acc;
    __syncthreads();
    if (threadIdx.x == 0)
        out[0] = smem[0] + smem[1] + smem[2] + smem[3];
}

extern "C" void kernel_launch(void* const* d_in, const int* in_sizes, int n_in,
                              void* d_out, int out_size, void* d_ws, size_t ws_size,
                              hipStream_t stream) {
    const float* pred = (const float*)d_in[0];
    const float* targ = (const float*)d_in[1];
    float* out     = (float*)d_out;
    float* partial = (float*)d_ws;   // BLOCKS floats, fully overwritten each call

    vol_loss_main<<<BLOCKS, THREADS, 0, stream>>>(pred, targ, partial);
    vol_loss_reduce<<<1, 256, 0, stream>>>(partial, out);
}